// Round 17
// baseline (177.396 us; speedup 1.0000x reference)
//
#include <hip/hip_runtime.h>

// B=4, S=2048, D=1024, H=16, HS=64. Full bf16-MFMA pipeline.
// Workspace layout (needs ~104 MiB):
//   Xb     @ 0         : x as bf16            [8192][1024]   16 MiB
//   WqkvT  @ 16777216  : qkv weights B^T bf16 [3072][1024]    6 MiB
//   WoT    @ 23068672  : Wo^T bf16            [1024][1024]    2 MiB
//   QKV    @ 25165824  : Q|K|V bf16           [8192][3072]   48 MiB
//   VT     @ 75497472  : V^T bf16, kappa-ordered keys  [64bh][64][2048] 16 MiB
//   AttnO  @ 92274688  : attention out bf16   [8192][1024]   16 MiB

typedef __bf16 bf16;
typedef bf16 bf16x8 __attribute__((ext_vector_type(8)));
typedef bf16 bf16x4 __attribute__((ext_vector_type(4)));
typedef float f32x4 __attribute__((ext_vector_type(4)));

__device__ __forceinline__ void gload16(const void* gsrc, void* ldst) {
  __builtin_amdgcn_global_load_lds(
      (const __attribute__((address_space(1))) unsigned int*)gsrc,
      (__attribute__((address_space(3))) unsigned int*)ldst, 16, 0, 0);
}

__device__ __forceinline__ f32x4 mfma16(bf16x8 a, bf16x8 b, f32x4 c) {
  return __builtin_amdgcn_mfma_f32_16x16x32_bf16(a, b, c, 0, 0, 0);
}

// ---------------- fused pack kernel (one launch) ----------------
__global__ __launch_bounds__(256) void pack_all_kernel(const float* __restrict__ x,
                                                       const float* __restrict__ Wq,
                                                       const float* __restrict__ Wk,
                                                       const float* __restrict__ Wv,
                                                       const float* __restrict__ Wo,
                                                       bf16* __restrict__ xb,
                                                       bf16* __restrict__ WT,
                                                       bf16* __restrict__ WoT) {
  const int stride = gridDim.x * 256;
  const int t0 = blockIdx.x * 256 + threadIdx.x;
  for (int i = t0; i < 2097152; i += stride) {
    float4 v = *(const float4*)(x + (size_t)i * 4);
    bf16x4 o;
    o[0] = (bf16)v.x; o[1] = (bf16)v.y; o[2] = (bf16)v.z; o[3] = (bf16)v.w;
    *(bf16x4*)(xb + (size_t)i * 4) = o;
  }
  for (int idx = t0; idx < 3145728; idx += stride) {
    int n = idx >> 10, k = idx & 1023;
    int sel = n >> 10, nn = n & 1023;
    const float* W = (sel == 0) ? Wq : (sel == 1 ? Wk : Wv);
    int h = nn >> 6, e = nn & 63;
    WT[(size_t)n * 1024 + k] = (bf16)W[h * 65536 + k * 64 + e];
  }
  for (int idx = t0; idx < 1048576; idx += stride) {
    int n = idx >> 10, k = idx & 1023;
    WoT[idx] = (bf16)Wo[k * 1024 + n];
  }
}

// ---------------- GEMM v7: 256x256 tile, 128x64 waves ----------------
// r16 model: gemm4 (64x64 waves, 32 FLOP/LDS-byte) sits AT the b128 LDS-read
// ceiling (23 TB/s at 742 TF ~ m134's 85 B/cy). v7 raises the ratio 1.33x:
// BM=BN=256, 512 threads, 8 waves (2M x 4N) -> per-wave 128x64 output
// (42.7 FLOP/LDS-byte). Sync skeleton is gemm4's PROVEN one, unchanged:
// stage(t+1) at tile top -> ds_read+MFMA (compiler-interleaved lgkm) ->
// vmcnt(0) (free: loads issued ~2300cy earlier, L2-hit) -> one barrier.
// kk-outer register scheme: acc 8x4 f32x4 =128 VGPR + af[8] 32 + bfr[4] 16.
// LDS 2 slots x (A 32KB + B 32KB) = 128KB -> 1 block/CU (2 waves/SIMD).
// Same 3-bit XOR chunk swizzle; n-major-per-XCD map (xcd owns 4 m-panels
// = 2MB A L2-resident). Requires M=8192 (32 m-tiles), N%256==0.
template <bool F32OUT>
__global__ __launch_bounds__(512, 2) void gemm7_kernel(const bf16* __restrict__ A,
                                                       const bf16* __restrict__ BT,
                                                       bf16* __restrict__ Cb,
                                                       float* __restrict__ Cf,
                                                       const float* __restrict__ bias,
                                                       int N, int K) {
  __shared__ bf16 As[2][256 * 64];  // [slot][row][k], chunk-swizzled, 32KB
  __shared__ bf16 Bs[2][256 * 64];
  const int tid = threadIdx.x, lane = tid & 63, wave = tid >> 6;
  const int g = lane >> 4, c = lane & 15;
  const int wr = wave >> 2, wc = wave & 3;  // 2M x 4N
  const int bid = blockIdx.x;
  const int xcd = bid & 7, local = bid >> 3;
  const int m0 = (xcd * 4 + (local & 3)) * 256;
  const int n0 = (local >> 2) * 256;

  // stage: offset o = j*8192 + tid*16; row = j*64 + (tid>>3), chunk = tid&7;
  // source chunk = (tid&7) ^ (row&7), row&7 = (tid>>3)&7
  const int sch = (tid & 7) ^ ((tid >> 3) & 7);

#define STAGE7(T, S)                                                      \
  do {                                                                    \
    _Pragma("unroll") for (int j = 0; j < 4; ++j) {                       \
      const int r = j * 64 + (tid >> 3);                                  \
      const int ldso = j * 8192 + tid * 16;                               \
      gload16(A + (size_t)(m0 + r) * K + (T)*64 + sch * 8,                \
              (char*)&As[S][0] + ldso);                                   \
      gload16(BT + (size_t)(n0 + r) * K + (T)*64 + sch * 8,               \
              (char*)&Bs[S][0] + ldso);                                   \
    }                                                                     \
  } while (0)

  f32x4 acc[8][4] = {};
  const int nt = K >> 6;  // K-tiles of 64
  STAGE7(0, 0);
  asm volatile("s_waitcnt vmcnt(0)" ::: "memory");
  __builtin_amdgcn_sched_barrier(0);
  __builtin_amdgcn_s_barrier();
  __builtin_amdgcn_sched_barrier(0);

#pragma unroll 1
  for (int t = 0; t < nt; ++t) {
    const int s = t & 1;
    if (t + 1 < nt) STAGE7(t + 1, s ^ 1);
#pragma unroll
    for (int kk = 0; kk < 2; ++kk) {
      bf16x8 af[8], bfr[4];
#pragma unroll
      for (int m = 0; m < 8; ++m) {
        const int row = wr * 128 + m * 16 + c;
        af[m] = *(const bf16x8*)((const char*)&As[s][0] + row * 128 +
                                 (((kk * 4 + g) ^ (row & 7)) << 4));
      }
#pragma unroll
      for (int n = 0; n < 4; ++n) {
        const int row = wc * 64 + n * 16 + c;
        bfr[n] = *(const bf16x8*)((const char*)&Bs[s][0] + row * 128 +
                                  (((kk * 4 + g) ^ (row & 7)) << 4));
      }
      // no lgkm drain: compiler interleaves reads/MFMAs with counted lgkmcnt
      __builtin_amdgcn_s_setprio(1);
#pragma unroll
      for (int m = 0; m < 8; ++m)
#pragma unroll
        for (int n = 0; n < 4; ++n)
          acc[m][n] = mfma16(af[m], bfr[n], acc[m][n]);
      __builtin_amdgcn_s_setprio(0);
    }
    if (t + 1 < nt) {
      asm volatile("s_waitcnt vmcnt(0)" ::: "memory");  // next slot landed
      __builtin_amdgcn_sched_barrier(0);
      __builtin_amdgcn_s_barrier();
      __builtin_amdgcn_sched_barrier(0);
    }
  }
#undef STAGE7
  // epilogue (verified mapping)
#pragma unroll
  for (int m = 0; m < 8; ++m)
#pragma unroll
    for (int n = 0; n < 4; ++n)
#pragma unroll
      for (int i = 0; i < 4; ++i) {
        int row = m0 + wr * 128 + m * 16 + g * 4 + i;
        int col = n0 + wc * 64 + n * 16 + c;
        if (F32OUT)
          Cf[(size_t)row * N + col] = acc[m][n][i] + bias[col];
        else
          Cb[(size_t)row * N + col] = (bf16)acc[m][n][i];
      }
}

// ---------------- GEMM v4 (r12: out-projection, N=1024 fits 128^2) --------
template <bool F32OUT>
__global__ __launch_bounds__(256, 2) void gemm4_kernel(const bf16* __restrict__ A,
                                                       const bf16* __restrict__ BT,
                                                       bf16* __restrict__ Cb,
                                                       float* __restrict__ Cf,
                                                       const float* __restrict__ bias,
                                                       int N, int K) {
  __shared__ bf16 As[2][128 * 64];  // [slot][row][k], chunk-swizzled
  __shared__ bf16 Bs[2][128 * 64];
  const int tid = threadIdx.x, lane = tid & 63, wave = tid >> 6;
  const int g = lane >> 4, c = lane & 15;
  const int wr = wave >> 1, wc = wave & 1;
  const int bid = blockIdx.x;
  const int xcd = bid & 7, local = bid >> 3;
  const int m0 = (xcd * 8 + (local & 7)) * 128;
  const int n0 = (local >> 3) * 128;

  const int schunk = (lane & 7) ^ (lane >> 3);  // source k-chunk for staging

#define STAGE4(T, S)                                                      \
  do {                                                                    \
    _Pragma("unroll") for (int j = 0; j < 4; ++j) {                       \
      const int r = wave * 32 + j * 8 + (lane >> 3);                      \
      const int ldso = wave * 4096 + j * 1024 + lane * 16;                \
      gload16(A + (size_t)(m0 + r) * K + (T)*64 + schunk * 8,             \
              (char*)&As[S][0] + ldso);                                   \
      gload16(BT + (size_t)(n0 + r) * K + (T)*64 + schunk * 8,            \
              (char*)&Bs[S][0] + ldso);                                   \
    }                                                                     \
  } while (0)

  f32x4 acc[4][4] = {};
  const int nt = K >> 6;  // K-tiles of 64
  STAGE4(0, 0);
  asm volatile("s_waitcnt vmcnt(0)" ::: "memory");
  __builtin_amdgcn_sched_barrier(0);
  __builtin_amdgcn_s_barrier();
  __builtin_amdgcn_sched_barrier(0);

#pragma unroll 1
  for (int t = 0; t < nt; ++t) {
    const int s = t & 1;
    if (t + 1 < nt) STAGE4(t + 1, s ^ 1);
    bf16x8 af[4][2], bfr[4][2];
#pragma unroll
    for (int m = 0; m < 4; ++m) {
      const int row = wr * 64 + m * 16 + c;
#pragma unroll
      for (int kk = 0; kk < 2; ++kk)
        af[m][kk] = *(const bf16x8*)((const char*)&As[s][0] + row * 128 +
                                     (((kk * 4 + g) ^ (row & 7)) << 4));
    }
#pragma unroll
    for (int n = 0; n < 4; ++n) {
      const int row = wc * 64 + n * 16 + c;
#pragma unroll
      for (int kk = 0; kk < 2; ++kk)
        bfr[n][kk] = *(const bf16x8*)((const char*)&Bs[s][0] + row * 128 +
                                      (((kk * 4 + g) ^ (row & 7)) << 4));
    }
    __builtin_amdgcn_s_setprio(1);
#pragma unroll
    for (int kk = 0; kk < 2; ++kk)
#pragma unroll
      for (int m = 0; m < 4; ++m)
#pragma unroll
        for (int n = 0; n < 4; ++n)
          acc[m][n] = mfma16(af[m][kk], bfr[n][kk], acc[m][n]);
    __builtin_amdgcn_s_setprio(0);
    if (t + 1 < nt) {
      asm volatile("s_waitcnt vmcnt(0)" ::: "memory");  // next slot landed
      __builtin_amdgcn_sched_barrier(0);
      __builtin_amdgcn_s_barrier();
      __builtin_amdgcn_sched_barrier(0);
    }
  }
#undef STAGE4
#pragma unroll
  for (int m = 0; m < 4; ++m)
#pragma unroll
    for (int n = 0; n < 4; ++n)
#pragma unroll
      for (int i = 0; i < 4; ++i) {
        int row = m0 + wr * 64 + m * 16 + g * 4 + i;
        int col = n0 + wc * 64 + n * 16 + c;
        if (F32OUT)
          Cf[(size_t)row * N + col] = acc[m][n][i] + bias[col];
        else
          Cb[(size_t)row * N + col] = (bf16)acc[m][n][i];
      }
}

// ---------------- V transpose: VT[bh][d][pos] with kappa-ordered keys ------
__global__ __launch_bounds__(256) void transpose_v_kernel(const bf16* __restrict__ qkv,
                                                          bf16* __restrict__ vt) {
  __shared__ bf16 tl[64][72];  // stride 144B keeps 16B alignment for b128 stores
  const int tid = threadIdx.x;
  const int st = blockIdx.x, bh = blockIdx.y;
  const int b = bh >> 4, h = bh & 15;
#pragma unroll
  for (int it = 0; it < 2; ++it) {
    int idx = it * 256 + tid;          // 0..511
    int sl = idx >> 3, ch = idx & 7;   // sl 0..63 (s row), ch 0..7 (d chunk)
    bf16x8 v = *(const bf16x8*)(qkv + (size_t)(b * 2048 + st * 64 + sl) * 3072 + 2048 + h * 64 + ch * 8);
    *(bf16x8*)&tl[sl][ch * 8] = v;
  }
  __syncthreads();
#pragma unroll
  for (int it = 0; it < 2; ++it) {
    int idx = it * 256 + tid;
    int d = idx >> 3, ch = idx & 7;    // d 0..63, output chunk 0..7 (8 keys)
    const int blk = ch >> 2, g = ch & 3;  // 32-key block, frag group
    bf16x8 o;
#pragma unroll
    for (int j = 0; j < 8; ++j) {
      int loc = (j < 4) ? (4 * g + j) : (16 + 4 * g + (j - 4));  // kappa
      o[j] = tl[blk * 32 + loc][d];
    }
    *(bf16x8*)(vt + ((size_t)bh * 64 + d) * 2048 + st * 64 + ch * 8) = o;
  }
}

// ---------------- causal flash attention (r15 best version) ----------------
// Grid = 512 blocks x 512 threads (8 waves, 16 q-rows/wave), KVBLK=128.
// bh-major XCD mapping. Block does qt=x then 15-x. Single-barrier-per-tile
// skeleton; kappa-ordered VT; tree-max; defer-max (T13, THR=8).
__global__ __launch_bounds__(512, 4) void attn_kernel(const bf16* __restrict__ qkv,
                                                      const bf16* __restrict__ vt,
                                                      bf16* __restrict__ attn_out) {
  __shared__ bf16 Ks[2][128 * 64];   // [key][hd], chunk-swizzled, 16KB each
  __shared__ bf16 Vs[2][64 * 128];   // [d][kpos], chunk-swizzled, 16KB each
  const int tid = threadIdx.x, lane = tid & 63, wave = tid >> 6;
  const int g = lane >> 4, c = lane & 15;
  const int bid = blockIdx.x;
  const int xcd = bid & 7;
  const int x = (bid >> 3) & 7;
  const int bh = (bid >> 6) * 8 + xcd;
  const int b = bh >> 4, h = bh & 15;
  const float SCL = 0.125f * 1.4426950408889634f;  // log2(e) * scale

  bf16x8 ones;
#pragma unroll
  for (int j = 0; j < 8; ++j) ones[j] = (bf16)1.0f;

#define STAGE(KT, BUF)                                                                    \
  do {                                                                                    \
    _Pragma("unroll") for (int t2 = 0; t2 < 2; ++t2) {                                    \
      int o = t2 * 8192 + wave * 1024 + lane * 16; /* 0..16383 */                         \
      int rK = o >> 7, chK = (((o & 127) >> 4) ^ (rK & 7));                               \
      gload16((const char*)qkv +                                                          \
                  ((size_t)(b * 2048 + (KT)*128 + rK) * 3072 + 1024 + h * 64) * 2 +       \
                  (chK << 4),                                                             \
              (char*)Ks[BUF] + o);                                                        \
      int rV = o >> 8, chV = (((o & 255) >> 4) ^ (rV & 7));                               \
      gload16((const char*)vt + (((size_t)bh * 64 + rV) * 2048 + (KT)*128) * 2 +          \
                  (chV << 4),                                                             \
              (char*)Vs[BUF] + o);                                                        \
    }                                                                                     \
  } while (0)

#pragma unroll 1
  for (int ph = 0; ph < 2; ++ph) {
    const int qt = ph ? (15 - x) : x;
    const int qlow = qt * 128 + wave * 16;  // lowest q row of this wave

    bf16x8 qf[2];
#pragma unroll
    for (int kk = 0; kk < 2; ++kk) {
      size_t row = (size_t)(b * 2048 + qlow + c);
      qf[kk] = *(const bf16x8*)(qkv + row * 3072 + h * 64 + kk * 32 + g * 8);
    }

    f32x4 oacc[4] = {};
    f32x4 lacc = {};        // row-sums, oacc layout (q = qlow + 4g+i)
    float mrun = -3.0e38f;  // per-lane: q = qlow + c

    const int nkt = qt + 1;
    __builtin_amdgcn_s_barrier();
    __builtin_amdgcn_sched_barrier(0);
    STAGE(0, 0);
    asm volatile("s_waitcnt vmcnt(0)" ::: "memory");
    __builtin_amdgcn_sched_barrier(0);
    __builtin_amdgcn_s_barrier();
    __builtin_amdgcn_sched_barrier(0);
    for (int kt = 0; kt < nkt; ++kt) {
      const int cur = kt & 1;
      if (kt + 1 < nkt) STAGE(kt + 1, cur ^ 1);
      // QK^T swapped: sc[n] holds S[key = kt*128+n*16+4g+i][q = qlow+c]
      f32x4 sc[8] = {};
      __builtin_amdgcn_s_setprio(1);
#pragma unroll
      for (int n = 0; n < 8; ++n) {
        int key = n * 16 + c;
#pragma unroll
        for (int kk = 0; kk < 2; ++kk) {
          bf16x8 kf = *(const bf16x8*)((const char*)Ks[cur] + key * 128 +
                                       (((kk * 4 + g) ^ (key & 7)) << 4));
          sc[n] = mfma16(kf, qf[kk], sc[n]);
        }
      }
      __builtin_amdgcn_s_setprio(0);
      const int q = qlow + c;
      if (kt == qt) {  // diagonal tile: causal mask
#pragma unroll
        for (int n = 0; n < 8; ++n)
#pragma unroll
          for (int i = 0; i < 4; ++i)
            sc[n][i] = ((kt * 128 + n * 16 + 4 * g + i) <= q) ? sc[n][i] : -3.0e38f;
      }
      // tree max (depth ~5)
      float vmax;
      {
        float a[8];
#pragma unroll
        for (int n = 0; n < 8; ++n)
          a[n] = fmaxf(fmaxf(sc[n][0], sc[n][1]), fmaxf(sc[n][2], sc[n][3]));
        float b0 = fmaxf(a[0], a[1]), b1 = fmaxf(a[2], a[3]);
        float b2 = fmaxf(a[4], a[5]), b3 = fmaxf(a[6], a[7]);
        vmax = fmaxf(fmaxf(b0, b1), fmaxf(b2, b3));
      }
      vmax = fmaxf(vmax, __shfl_xor(vmax, 16));
      vmax = fmaxf(vmax, __shfl_xor(vmax, 32));
      const float mx = vmax * SCL;
      // defer-max (T13): rescale only when running max grew by >8 (log2)
      if (!__all(mx <= mrun + 8.0f)) {
        const float mnew = fmaxf(mrun, mx);
        const float fs = __builtin_amdgcn_exp2f(mrun - mnew);
        mrun = mnew;
#pragma unroll
        for (int i = 0; i < 4; ++i) {
          float fsb = __shfl(fs, ((lane >> 4) << 2) + i);
          lacc[i] *= fsb;
#pragma unroll
          for (int dn = 0; dn < 4; ++dn) oacc[dn][i] *= fsb;
        }
      }
#pragma unroll
      for (int n = 0; n < 8; ++n)
#pragma unroll
        for (int i = 0; i < 4; ++i)
          sc[n][i] = __builtin_amdgcn_exp2f(fmaf(sc[n][i], SCL, -mrun));
      // pack PV A-frags: key = kss*32 + (j<4 ? 4g+j : 16+4g+(j-4))
      bf16x8 pa[4];
#pragma unroll
      for (int kss = 0; kss < 4; ++kss) {
        bf16x8 t;
#pragma unroll
        for (int j = 0; j < 4; ++j) t[j] = (bf16)sc[2 * kss][j];
#pragma unroll
        for (int j = 0; j < 4; ++j) t[4 + j] = (bf16)sc[2 * kss + 1][j];
        pa[kss] = t;
      }
      // PV + row-sum via ones-MFMA; kappa-ordered Vs -> one b128 per (kss,dn)
      __builtin_amdgcn_s_setprio(1);
#pragma unroll
      for (int kss = 0; kss < 4; ++kss) {
        lacc = mfma16(pa[kss], ones, lacc);
#pragma unroll
        for (int dn = 0; dn < 4; ++dn) {
          const int d = dn * 16 + c;
          bf16x8 vb = *(const bf16x8*)((const char*)Vs[cur] + d * 256 +
                                       (((kss * 4 + g) ^ (d & 7)) << 4));
          oacc[dn] = mfma16(pa[kss], vb, oacc[dn]);
        }
      }
      __builtin_amdgcn_s_setprio(0);
      if (kt + 1 < nkt) {
        asm volatile("s_waitcnt vmcnt(0)" ::: "memory");  // kt+1 landed (free)
        __builtin_amdgcn_sched_barrier(0);
        __builtin_amdgcn_s_barrier();  // publish kt+1; readers of cur done
        __builtin_amdgcn_sched_barrier(0);
      }
    }
    // epilogue: normalize, store bf16 [8192][1024]
#pragma unroll
    for (int i = 0; i < 4; ++i) {
      float inv = __builtin_amdgcn_rcpf(lacc[i]);
      size_t row = (size_t)(b * 2048 + qlow + 4 * g + i);
#pragma unroll
      for (int dn = 0; dn < 4; ++dn)
        attn_out[row * 1024 + h * 64 + dn * 16 + c] = (bf16)(oacc[dn][i] * inv);
    }
  }
#undef STAGE
}

// ---------------- launch ----------------
extern "C" void kernel_launch(void* const* d_in, const int* in_sizes, int n_in,
                              void* d_out, int out_size, void* d_ws, size_t ws_size,
                              hipStream_t stream) {
  const float* x  = (const float*)d_in[0];
  const float* Wq = (const float*)d_in[1];
  const float* Wk = (const float*)d_in[2];
  const float* Wv = (const float*)d_in[3];
  const float* Wo = (const float*)d_in[4];
  const float* bo = (const float*)d_in[5];
  float* out = (float*)d_out;
  char* ws = (char*)d_ws;

  bf16* Xb    = (bf16*)(ws);
  bf16* WqkvT = (bf16*)(ws + 16777216);
  bf16* WoT   = (bf16*)(ws + 23068672);
  bf16* QKV   = (bf16*)(ws + 25165824);
  bf16* VT    = (bf16*)(ws + 75497472);
  bf16* AttnO = (bf16*)(ws + 92274688);

  pack_all_kernel<<<2048, 256, 0, stream>>>(x, Wq, Wk, Wv, Wo, Xb, WqkvT, WoT);
  gemm7_kernel<false><<<384, 512, 0, stream>>>(Xb, WqkvT, QKV, nullptr, nullptr,
                                               3072, 1024);
  transpose_v_kernel<<<dim3(32, 64), 256, 0, stream>>>(QKV, VT);
  attn_kernel<<<512, 512, 0, stream>>>(QKV, VT, AttnO);
  gemm4_kernel<true><<<512, 256, 0, stream>>>(AttnO, WoT, nullptr, out, bo,
                                              1024, 1024);
}

// Round 18
// 174.163 us; speedup vs baseline: 1.0186x; 1.0186x over previous
//
#include <hip/hip_runtime.h>

// B=4, S=2048, D=1024, H=16, HS=64. Full bf16-MFMA pipeline.
// Workspace layout (needs ~104 MiB):
//   Xb     @ 0         : x as bf16            [8192][1024]   16 MiB
//   WqkvT  @ 16777216  : qkv weights B^T bf16 [3072][1024]    6 MiB
//   WoT    @ 23068672  : Wo^T bf16            [1024][1024]    2 MiB
//   QKV    @ 25165824  : Q|K|V bf16           [8192][3072]   48 MiB
//   VT     @ 75497472  : V^T bf16, kappa-ordered keys  [64bh][64][2048] 16 MiB
//   AttnO  @ 92274688  : attention out bf16   [8192][1024]   16 MiB

typedef __bf16 bf16;
typedef bf16 bf16x8 __attribute__((ext_vector_type(8)));
typedef bf16 bf16x4 __attribute__((ext_vector_type(4)));
typedef float f32x4 __attribute__((ext_vector_type(4)));

__device__ __forceinline__ void gload16(const void* gsrc, void* ldst) {
  __builtin_amdgcn_global_load_lds(
      (const __attribute__((address_space(1))) unsigned int*)gsrc,
      (__attribute__((address_space(3))) unsigned int*)ldst, 16, 0, 0);
}

__device__ __forceinline__ f32x4 mfma16(bf16x8 a, bf16x8 b, f32x4 c) {
  return __builtin_amdgcn_mfma_f32_16x16x32_bf16(a, b, c, 0, 0, 0);
}

// ---------------- fused pack kernel (one launch) ----------------
__global__ __launch_bounds__(256) void pack_all_kernel(const float* __restrict__ x,
                                                       const float* __restrict__ Wq,
                                                       const float* __restrict__ Wk,
                                                       const float* __restrict__ Wv,
                                                       const float* __restrict__ Wo,
                                                       bf16* __restrict__ xb,
                                                       bf16* __restrict__ WT,
                                                       bf16* __restrict__ WoT) {
  const int stride = gridDim.x * 256;
  const int t0 = blockIdx.x * 256 + threadIdx.x;
  for (int i = t0; i < 2097152; i += stride) {
    float4 v = *(const float4*)(x + (size_t)i * 4);
    bf16x4 o;
    o[0] = (bf16)v.x; o[1] = (bf16)v.y; o[2] = (bf16)v.z; o[3] = (bf16)v.w;
    *(bf16x4*)(xb + (size_t)i * 4) = o;
  }
  for (int idx = t0; idx < 3145728; idx += stride) {
    int n = idx >> 10, k = idx & 1023;
    int sel = n >> 10, nn = n & 1023;
    const float* W = (sel == 0) ? Wq : (sel == 1 ? Wk : Wv);
    int h = nn >> 6, e = nn & 63;
    WT[(size_t)n * 1024 + k] = (bf16)W[h * 65536 + k * 64 + e];
  }
  for (int idx = t0; idx < 1048576; idx += stride) {
    int n = idx >> 10, k = idx & 1023;
    WoT[idx] = (bf16)Wo[k * 1024 + n];
  }
}

// ---------------- GEMM v8: m201-style 8-phase, 256x256, BK=64 ----------------
// Fragment/swizzle/epilogue math = gemm7 (r17-VALIDATED via absmax pass); only
// the schedule is new. 512 threads = 8 waves (2M x 4N), per-wave 128x64.
// LDS: As/Bs[2 slot][2 half][128x64] = 128KB, 1 block/CU. slot(t) = t&1.
// Per K-tile t: 4 phases q (kk=q&1, mh=q>>1), each {4 ds_read af (+8 bfr at
// q0) | stage one half of tile t+1 into slot (t+1)&1 | barrier | lgkmcnt(0) |
// 16 MFMA (setprio) | barrier}. Tile boundary: vmcnt(0) (stages issued >=1
// phase earlier, L2-hit) + barrier. Hazards: tile-t data published by the
// t-1 boundary; slot-(t+1) overwrite is barrier-separated from its last
// readers (tile t-1); in-tile stages never touch the read slot.
template <bool F32OUT>
__global__ __launch_bounds__(512, 2) void gemm8_kernel(const bf16* __restrict__ A,
                                                       const bf16* __restrict__ BT,
                                                       bf16* __restrict__ Cb,
                                                       float* __restrict__ Cf,
                                                       const float* __restrict__ bias,
                                                       int N, int K) {
  __shared__ bf16 As[2][2][128 * 64];  // [slot][half][lrow][k], 16KB regions
  __shared__ bf16 Bs[2][2][128 * 64];
  const int tid = threadIdx.x, lane = tid & 63, wave = tid >> 6;
  const int g = lane >> 4, c = lane & 15;
  const int wr = wave >> 2, wc = wave & 3;  // 2M x 4N
  const int bid = blockIdx.x;
  const int xcd = bid & 7, local = bid >> 3;
  const int m0 = (xcd * 4 + (local & 3)) * 256;
  const int n0 = (local >> 2) * 256;
  const int sch = (tid & 7) ^ ((tid >> 3) & 7);  // pre-swizzled source chunk
  const int rs = tid >> 3;                       // staged row within 64-group

#define STG_A8(T, H)                                                          \
  do {                                                                        \
    const int sl_ = (T)&1;                                                    \
    _Pragma("unroll") for (int j = 0; j < 2; ++j)                             \
        gload16(A + (size_t)(m0 + (H)*128 + j * 64 + rs) * K + (T)*64 + sch * 8, \
                (char*)&As[sl_][H][0] + j * 8192 + tid * 16);                 \
  } while (0)
#define STG_B8(T, H)                                                          \
  do {                                                                        \
    const int sl_ = (T)&1;                                                    \
    _Pragma("unroll") for (int j = 0; j < 2; ++j)                             \
        gload16(BT + (size_t)(n0 + (H)*128 + j * 64 + rs) * K + (T)*64 + sch * 8, \
                (char*)&Bs[sl_][H][0] + j * 8192 + tid * 16);                 \
  } while (0)

  f32x4 acc[8][4] = {};
  const int nt = K >> 6;  // 16 K-tiles
  STG_A8(0, 0); STG_A8(0, 1); STG_B8(0, 0); STG_B8(0, 1);
  asm volatile("s_waitcnt vmcnt(0)" ::: "memory");
  __builtin_amdgcn_sched_barrier(0);
  __builtin_amdgcn_s_barrier();
  __builtin_amdgcn_sched_barrier(0);

#pragma unroll 1
  for (int t = 0; t < nt; ++t) {
    const int s = t & 1;
    const char* Ar = (const char*)&As[s][wr][0];
    const char* Br = (const char*)&Bs[s][wc >> 1][0];
    bf16x8 bfr[4][2];
#pragma unroll
    for (int q = 0; q < 4; ++q) {
      const int kk = q & 1, mh = q >> 1;
      bf16x8 af[4];
#pragma unroll
      for (int mf = 0; mf < 4; ++mf) {
        const int lr = mh * 64 + mf * 16 + c;
        af[mf] = *(const bf16x8*)(Ar + lr * 128 + (((kk * 4 + g) ^ (lr & 7)) << 4));
      }
      if (q == 0) {
#pragma unroll
        for (int nf = 0; nf < 4; ++nf) {
          const int lr = (wc & 1) * 64 + nf * 16 + c;
#pragma unroll
          for (int k2 = 0; k2 < 2; ++k2)
            bfr[nf][k2] = *(const bf16x8*)(Br + lr * 128 +
                                           (((k2 * 4 + g) ^ (lr & 7)) << 4));
        }
      }
      if (t + 1 < nt) {
        if (q == 0) STG_A8(t + 1, 0);
        else if (q == 1) STG_A8(t + 1, 1);
        else if (q == 2) STG_B8(t + 1, 0);
        else STG_B8(t + 1, 1);
      }
      __builtin_amdgcn_sched_barrier(0);
      __builtin_amdgcn_s_barrier();
      asm volatile("s_waitcnt lgkmcnt(0)" ::: "memory");
      __builtin_amdgcn_sched_barrier(0);
      __builtin_amdgcn_s_setprio(1);
#pragma unroll
      for (int mf = 0; mf < 4; ++mf)
#pragma unroll
        for (int nf = 0; nf < 4; ++nf)
          acc[mh * 4 + mf][nf] = mfma16(af[mf], bfr[nf][kk], acc[mh * 4 + mf][nf]);
      __builtin_amdgcn_s_setprio(0);
      __builtin_amdgcn_sched_barrier(0);
      if (q < 3) {
        __builtin_amdgcn_s_barrier();
        __builtin_amdgcn_sched_barrier(0);
      }
    }
    if (t + 1 < nt) {
      asm volatile("s_waitcnt vmcnt(0)" ::: "memory");  // t+1 halves landed (>=1 phase slack)
      __builtin_amdgcn_sched_barrier(0);
      __builtin_amdgcn_s_barrier();
      __builtin_amdgcn_sched_barrier(0);
    }
  }
#undef STG_A8
#undef STG_B8
  // epilogue (gemm7's r17-validated mapping)
#pragma unroll
  for (int m = 0; m < 8; ++m)
#pragma unroll
    for (int n = 0; n < 4; ++n)
#pragma unroll
      for (int i = 0; i < 4; ++i) {
        int row = m0 + wr * 128 + m * 16 + g * 4 + i;
        int col = n0 + wc * 64 + n * 16 + c;
        if (F32OUT)
          Cf[(size_t)row * N + col] = acc[m][n][i] + bias[col];
        else
          Cb[(size_t)row * N + col] = (bf16)acc[m][n][i];
      }
}

// ---------------- GEMM v4 (r12: out-projection, N=1024 fits 128^2) --------
template <bool F32OUT>
__global__ __launch_bounds__(256, 2) void gemm4_kernel(const bf16* __restrict__ A,
                                                       const bf16* __restrict__ BT,
                                                       bf16* __restrict__ Cb,
                                                       float* __restrict__ Cf,
                                                       const float* __restrict__ bias,
                                                       int N, int K) {
  __shared__ bf16 As[2][128 * 64];  // [slot][row][k], chunk-swizzled
  __shared__ bf16 Bs[2][128 * 64];
  const int tid = threadIdx.x, lane = tid & 63, wave = tid >> 6;
  const int g = lane >> 4, c = lane & 15;
  const int wr = wave >> 1, wc = wave & 1;
  const int bid = blockIdx.x;
  const int xcd = bid & 7, local = bid >> 3;
  const int m0 = (xcd * 8 + (local & 7)) * 128;
  const int n0 = (local >> 3) * 128;

  const int schunk = (lane & 7) ^ (lane >> 3);  // source k-chunk for staging

#define STAGE4(T, S)                                                      \
  do {                                                                    \
    _Pragma("unroll") for (int j = 0; j < 4; ++j) {                       \
      const int r = wave * 32 + j * 8 + (lane >> 3);                      \
      const int ldso = wave * 4096 + j * 1024 + lane * 16;                \
      gload16(A + (size_t)(m0 + r) * K + (T)*64 + schunk * 8,             \
              (char*)&As[S][0] + ldso);                                   \
      gload16(BT + (size_t)(n0 + r) * K + (T)*64 + schunk * 8,            \
              (char*)&Bs[S][0] + ldso);                                   \
    }                                                                     \
  } while (0)

  f32x4 acc[4][4] = {};
  const int nt = K >> 6;  // K-tiles of 64
  STAGE4(0, 0);
  asm volatile("s_waitcnt vmcnt(0)" ::: "memory");
  __builtin_amdgcn_sched_barrier(0);
  __builtin_amdgcn_s_barrier();
  __builtin_amdgcn_sched_barrier(0);

#pragma unroll 1
  for (int t = 0; t < nt; ++t) {
    const int s = t & 1;
    if (t + 1 < nt) STAGE4(t + 1, s ^ 1);
    bf16x8 af[4][2], bfr[4][2];
#pragma unroll
    for (int m = 0; m < 4; ++m) {
      const int row = wr * 64 + m * 16 + c;
#pragma unroll
      for (int kk = 0; kk < 2; ++kk)
        af[m][kk] = *(const bf16x8*)((const char*)&As[s][0] + row * 128 +
                                     (((kk * 4 + g) ^ (row & 7)) << 4));
    }
#pragma unroll
    for (int n = 0; n < 4; ++n) {
      const int row = wc * 64 + n * 16 + c;
#pragma unroll
      for (int kk = 0; kk < 2; ++kk)
        bfr[n][kk] = *(const bf16x8*)((const char*)&Bs[s][0] + row * 128 +
                                      (((kk * 4 + g) ^ (row & 7)) << 4));
    }
    __builtin_amdgcn_s_setprio(1);
#pragma unroll
    for (int kk = 0; kk < 2; ++kk)
#pragma unroll
      for (int m = 0; m < 4; ++m)
#pragma unroll
        for (int n = 0; n < 4; ++n)
          acc[m][n] = mfma16(af[m][kk], bfr[n][kk], acc[m][n]);
    __builtin_amdgcn_s_setprio(0);
    if (t + 1 < nt) {
      asm volatile("s_waitcnt vmcnt(0)" ::: "memory");  // next slot landed
      __builtin_amdgcn_sched_barrier(0);
      __builtin_amdgcn_s_barrier();
      __builtin_amdgcn_sched_barrier(0);
    }
  }
#undef STAGE4
#pragma unroll
  for (int m = 0; m < 4; ++m)
#pragma unroll
    for (int n = 0; n < 4; ++n)
#pragma unroll
      for (int i = 0; i < 4; ++i) {
        int row = m0 + wr * 64 + m * 16 + g * 4 + i;
        int col = n0 + wc * 64 + n * 16 + c;
        if (F32OUT)
          Cf[(size_t)row * N + col] = acc[m][n][i] + bias[col];
        else
          Cb[(size_t)row * N + col] = (bf16)acc[m][n][i];
      }
}

// ---------------- V transpose: VT[bh][d][pos] with kappa-ordered keys ------
__global__ __launch_bounds__(256) void transpose_v_kernel(const bf16* __restrict__ qkv,
                                                          bf16* __restrict__ vt) {
  __shared__ bf16 tl[64][72];  // stride 144B keeps 16B alignment for b128 stores
  const int tid = threadIdx.x;
  const int st = blockIdx.x, bh = blockIdx.y;
  const int b = bh >> 4, h = bh & 15;
#pragma unroll
  for (int it = 0; it < 2; ++it) {
    int idx = it * 256 + tid;          // 0..511
    int sl = idx >> 3, ch = idx & 7;   // sl 0..63 (s row), ch 0..7 (d chunk)
    bf16x8 v = *(const bf16x8*)(qkv + (size_t)(b * 2048 + st * 64 + sl) * 3072 + 2048 + h * 64 + ch * 8);
    *(bf16x8*)&tl[sl][ch * 8] = v;
  }
  __syncthreads();
#pragma unroll
  for (int it = 0; it < 2; ++it) {
    int idx = it * 256 + tid;
    int d = idx >> 3, ch = idx & 7;    // d 0..63, output chunk 0..7 (8 keys)
    const int blk = ch >> 2, g = ch & 3;  // 32-key block, frag group
    bf16x8 o;
#pragma unroll
    for (int j = 0; j < 8; ++j) {
      int loc = (j < 4) ? (4 * g + j) : (16 + 4 * g + (j - 4));  // kappa
      o[j] = tl[blk * 32 + loc][d];
    }
    *(bf16x8*)(vt + ((size_t)bh * 64 + d) * 2048 + st * 64 + ch * 8) = o;
  }
}

// ---------------- causal flash attention (r15 best version) ----------------
__global__ __launch_bounds__(512, 4) void attn_kernel(const bf16* __restrict__ qkv,
                                                      const bf16* __restrict__ vt,
                                                      bf16* __restrict__ attn_out) {
  __shared__ bf16 Ks[2][128 * 64];   // [key][hd], chunk-swizzled, 16KB each
  __shared__ bf16 Vs[2][64 * 128];   // [d][kpos], chunk-swizzled, 16KB each
  const int tid = threadIdx.x, lane = tid & 63, wave = tid >> 6;
  const int g = lane >> 4, c = lane & 15;
  const int bid = blockIdx.x;
  const int xcd = bid & 7;
  const int x = (bid >> 3) & 7;
  const int bh = (bid >> 6) * 8 + xcd;
  const int b = bh >> 4, h = bh & 15;
  const float SCL = 0.125f * 1.4426950408889634f;  // log2(e) * scale

  bf16x8 ones;
#pragma unroll
  for (int j = 0; j < 8; ++j) ones[j] = (bf16)1.0f;

#define STAGE(KT, BUF)                                                                    \
  do {                                                                                    \
    _Pragma("unroll") for (int t2 = 0; t2 < 2; ++t2) {                                    \
      int o = t2 * 8192 + wave * 1024 + lane * 16; /* 0..16383 */                         \
      int rK = o >> 7, chK = (((o & 127) >> 4) ^ (rK & 7));                               \
      gload16((const char*)qkv +                                                          \
                  ((size_t)(b * 2048 + (KT)*128 + rK) * 3072 + 1024 + h * 64) * 2 +       \
                  (chK << 4),                                                             \
              (char*)Ks[BUF] + o);                                                        \
      int rV = o >> 8, chV = (((o & 255) >> 4) ^ (rV & 7));                               \
      gload16((const char*)vt + (((size_t)bh * 64 + rV) * 2048 + (KT)*128) * 2 +          \
                  (chV << 4),                                                             \
              (char*)Vs[BUF] + o);                                                        \
    }                                                                                     \
  } while (0)

#pragma unroll 1
  for (int ph = 0; ph < 2; ++ph) {
    const int qt = ph ? (15 - x) : x;
    const int qlow = qt * 128 + wave * 16;  // lowest q row of this wave

    bf16x8 qf[2];
#pragma unroll
    for (int kk = 0; kk < 2; ++kk) {
      size_t row = (size_t)(b * 2048 + qlow + c);
      qf[kk] = *(const bf16x8*)(qkv + row * 3072 + h * 64 + kk * 32 + g * 8);
    }

    f32x4 oacc[4] = {};
    f32x4 lacc = {};        // row-sums, oacc layout (q = qlow + 4g+i)
    float mrun = -3.0e38f;  // per-lane: q = qlow + c

    const int nkt = qt + 1;
    __builtin_amdgcn_s_barrier();
    __builtin_amdgcn_sched_barrier(0);
    STAGE(0, 0);
    asm volatile("s_waitcnt vmcnt(0)" ::: "memory");
    __builtin_amdgcn_sched_barrier(0);
    __builtin_amdgcn_s_barrier();
    __builtin_amdgcn_sched_barrier(0);
    for (int kt = 0; kt < nkt; ++kt) {
      const int cur = kt & 1;
      if (kt + 1 < nkt) STAGE(kt + 1, cur ^ 1);
      // QK^T swapped: sc[n] holds S[key = kt*128+n*16+4g+i][q = qlow+c]
      f32x4 sc[8] = {};
      __builtin_amdgcn_s_setprio(1);
#pragma unroll
      for (int n = 0; n < 8; ++n) {
        int key = n * 16 + c;
#pragma unroll
        for (int kk = 0; kk < 2; ++kk) {
          bf16x8 kf = *(const bf16x8*)((const char*)Ks[cur] + key * 128 +
                                       (((kk * 4 + g) ^ (key & 7)) << 4));
          sc[n] = mfma16(kf, qf[kk], sc[n]);
        }
      }
      __builtin_amdgcn_s_setprio(0);
      const int q = qlow + c;
      if (kt == qt) {  // diagonal tile: causal mask
#pragma unroll
        for (int n = 0; n < 8; ++n)
#pragma unroll
          for (int i = 0; i < 4; ++i)
            sc[n][i] = ((kt * 128 + n * 16 + 4 * g + i) <= q) ? sc[n][i] : -3.0e38f;
      }
      // tree max (depth ~5)
      float vmax;
      {
        float a[8];
#pragma unroll
        for (int n = 0; n < 8; ++n)
          a[n] = fmaxf(fmaxf(sc[n][0], sc[n][1]), fmaxf(sc[n][2], sc[n][3]));
        float b0 = fmaxf(a[0], a[1]), b1 = fmaxf(a[2], a[3]);
        float b2 = fmaxf(a[4], a[5]), b3 = fmaxf(a[6], a[7]);
        vmax = fmaxf(fmaxf(b0, b1), fmaxf(b2, b3));
      }
      vmax = fmaxf(vmax, __shfl_xor(vmax, 16));
      vmax = fmaxf(vmax, __shfl_xor(vmax, 32));
      const float mx = vmax * SCL;
      // defer-max (T13): rescale only when running max grew by >8 (log2)
      if (!__all(mx <= mrun + 8.0f)) {
        const float mnew = fmaxf(mrun, mx);
        const float fs = __builtin_amdgcn_exp2f(mrun - mnew);
        mrun = mnew;
#pragma unroll
        for (int i = 0; i < 4; ++i) {
          float fsb = __shfl(fs, ((lane >> 4) << 2) + i);
          lacc[i] *= fsb;
#pragma unroll
          for (int dn = 0; dn < 4; ++dn) oacc[dn][i] *= fsb;
        }
      }
#pragma unroll
      for (int n = 0; n < 8; ++n)
#pragma unroll
        for (int i = 0; i < 4; ++i)
          sc[n][i] = __builtin_amdgcn_exp2f(fmaf(sc[n][i], SCL, -mrun));
      // pack PV A-frags: key = kss*32 + (j<4 ? 4g+j : 16+4g+(j-4))
      bf16x8 pa[4];
#pragma unroll
      for (int kss = 0; kss < 4; ++kss) {
        bf16x8 t;
#pragma unroll
        for (int j = 0; j < 4; ++j) t[j] = (bf16)sc[2 * kss][j];
#pragma unroll
        for (int j = 0; j < 4; ++j) t[4 + j] = (bf16)sc[2 * kss + 1][j];
        pa[kss] = t;
      }
      // PV + row-sum via ones-MFMA; kappa-ordered Vs -> one b128 per (kss,dn)
      __builtin_amdgcn_s_setprio(1);
#pragma unroll
      for (int kss = 0; kss < 4; ++kss) {
        lacc = mfma16(pa[kss], ones, lacc);
#pragma unroll
        for (int dn = 0; dn < 4; ++dn) {
          const int d = dn * 16 + c;
          bf16x8 vb = *(const bf16x8*)((const char*)Vs[cur] + d * 256 +
                                       (((kss * 4 + g) ^ (d & 7)) << 4));
          oacc[dn] = mfma16(pa[kss], vb, oacc[dn]);
        }
      }
      __builtin_amdgcn_s_setprio(0);
      if (kt + 1 < nkt) {
        asm volatile("s_waitcnt vmcnt(0)" ::: "memory");  // kt+1 landed (free)
        __builtin_amdgcn_sched_barrier(0);
        __builtin_amdgcn_s_barrier();  // publish kt+1; readers of cur done
        __builtin_amdgcn_sched_barrier(0);
      }
    }
    // epilogue: normalize, store bf16 [8192][1024]
#pragma unroll
    for (int i = 0; i < 4; ++i) {
      float inv = __builtin_amdgcn_rcpf(lacc[i]);
      size_t row = (size_t)(b * 2048 + qlow + 4 * g + i);
#pragma unroll
      for (int dn = 0; dn < 4; ++dn)
        attn_out[row * 1024 + h * 64 + dn * 16 + c] = (bf16)(oacc[dn][i] * inv);
    }
  }
#undef STAGE
}

// ---------------- launch ----------------
extern "C" void kernel_launch(void* const* d_in, const int* in_sizes, int n_in,
                              void* d_out, int out_size, void* d_ws, size_t ws_size,
                              hipStream_t stream) {
  const float* x  = (const float*)d_in[0];
  const float* Wq = (const float*)d_in[1];
  const float* Wk = (const float*)d_in[2];
  const float* Wv = (const float*)d_in[3];
  const float* Wo = (const float*)d_in[4];
  const float* bo = (const float*)d_in[5];
  float* out = (float*)d_out;
  char* ws = (char*)d_ws;

  bf16* Xb    = (bf16*)(ws);
  bf16* WqkvT = (bf16*)(ws + 16777216);
  bf16* WoT   = (bf16*)(ws + 23068672);
  bf16* QKV   = (bf16*)(ws + 25165824);
  bf16* VT    = (bf16*)(ws + 75497472);
  bf16* AttnO = (bf16*)(ws + 92274688);

  pack_all_kernel<<<2048, 256, 0, stream>>>(x, Wq, Wk, Wv, Wo, Xb, WqkvT, WoT);
  gemm8_kernel<false><<<384, 512, 0, stream>>>(Xb, WqkvT, QKV, nullptr, nullptr,
                                               3072, 1024);
  transpose_v_kernel<<<dim3(32, 64), 256, 0, stream>>>(QKV, VT);
  attn_kernel<<<512, 512, 0, stream>>>(QKV, VT, AttnO);
  gemm4_kernel<true><<<512, 256, 0, stream>>>(AttnO, WoT, nullptr, out, bo,
                                              1024, 1024);
}

// Round 19
// 167.696 us; speedup vs baseline: 1.0578x; 1.0386x over previous
//
#include <hip/hip_runtime.h>

// B=4, S=2048, D=1024, H=16, HS=64. Full bf16-MFMA pipeline.
// Workspace layout (needs ~104 MiB):
//   Xb     @ 0         : x as bf16            [8192][1024]   16 MiB
//   WqkvT  @ 16777216  : qkv weights B^T bf16 [3072][1024]    6 MiB
//   WoT    @ 23068672  : Wo^T bf16            [1024][1024]    2 MiB
//   QKV    @ 25165824  : Q|K|V bf16           [8192][3072]   48 MiB
//   VT     @ 75497472  : V^T bf16, kappa-ordered keys  [64bh][64][2048] 16 MiB
//   AttnO  @ 92274688  : attention out bf16   [8192][1024]   16 MiB

typedef __bf16 bf16;
typedef bf16 bf16x8 __attribute__((ext_vector_type(8)));
typedef bf16 bf16x4 __attribute__((ext_vector_type(4)));
typedef float f32x4 __attribute__((ext_vector_type(4)));

__device__ __forceinline__ void gload16(const void* gsrc, void* ldst) {
  __builtin_amdgcn_global_load_lds(
      (const __attribute__((address_space(1))) unsigned int*)gsrc,
      (__attribute__((address_space(3))) unsigned int*)ldst, 16, 0, 0);
}

__device__ __forceinline__ f32x4 mfma16(bf16x8 a, bf16x8 b, f32x4 c) {
  return __builtin_amdgcn_mfma_f32_16x16x32_bf16(a, b, c, 0, 0, 0);
}

// ---------------- fused pack kernel (one launch) ----------------
__global__ __launch_bounds__(256) void pack_all_kernel(const float* __restrict__ x,
                                                       const float* __restrict__ Wq,
                                                       const float* __restrict__ Wk,
                                                       const float* __restrict__ Wv,
                                                       const float* __restrict__ Wo,
                                                       bf16* __restrict__ xb,
                                                       bf16* __restrict__ WT,
                                                       bf16* __restrict__ WoT) {
  const int stride = gridDim.x * 256;
  const int t0 = blockIdx.x * 256 + threadIdx.x;
  for (int i = t0; i < 2097152; i += stride) {
    float4 v = *(const float4*)(x + (size_t)i * 4);
    bf16x4 o;
    o[0] = (bf16)v.x; o[1] = (bf16)v.y; o[2] = (bf16)v.z; o[3] = (bf16)v.w;
    *(bf16x4*)(xb + (size_t)i * 4) = o;
  }
  for (int idx = t0; idx < 3145728; idx += stride) {
    int n = idx >> 10, k = idx & 1023;
    int sel = n >> 10, nn = n & 1023;
    const float* W = (sel == 0) ? Wq : (sel == 1 ? Wk : Wv);
    int h = nn >> 6, e = nn & 63;
    WT[(size_t)n * 1024 + k] = (bf16)W[h * 65536 + k * 64 + e];
  }
  for (int idx = t0; idx < 1048576; idx += stride) {
    int n = idx >> 10, k = idx & 1023;
    WoT[idx] = (bf16)Wo[k * 1024 + n];
  }
}

// ---------------- GEMM v4 (session best: 69.6us): C = A * BT^T ----------------
// Per-wave 64x64 (32 FLOP per LDS byte), BM=BN=128, BK=64, 256 threads
// (4 waves 2x2), 2 LDS slots (64KB) -> 2 blocks/CU (m114 cross-block overlap
// is the winning mechanism; 7 structural variants bracketed this ceiling).
// One barrier + one vmcnt(0) per K-tile; no lgkm fence (compiler interleaves).
// 3-bit XOR chunk swizzle; n-major-per-XCD mapping (A panel + B L2-resident).
template <bool F32OUT>
__global__ __launch_bounds__(256, 2) void gemm4_kernel(const bf16* __restrict__ A,
                                                       const bf16* __restrict__ BT,
                                                       bf16* __restrict__ Cb,
                                                       float* __restrict__ Cf,
                                                       const float* __restrict__ bias,
                                                       int N, int K) {
  __shared__ bf16 As[2][128 * 64];  // [slot][row][k], chunk-swizzled
  __shared__ bf16 Bs[2][128 * 64];
  const int tid = threadIdx.x, lane = tid & 63, wave = tid >> 6;
  const int g = lane >> 4, c = lane & 15;
  const int wr = wave >> 1, wc = wave & 1;
  const int bid = blockIdx.x;
  const int xcd = bid & 7, local = bid >> 3;
  const int m0 = (xcd * 8 + (local & 7)) * 128;
  const int n0 = (local >> 3) * 128;

  const int schunk = (lane & 7) ^ (lane >> 3);  // source k-chunk for staging

#define STAGE4(T, S)                                                      \
  do {                                                                    \
    _Pragma("unroll") for (int j = 0; j < 4; ++j) {                       \
      const int r = wave * 32 + j * 8 + (lane >> 3);                      \
      const int ldso = wave * 4096 + j * 1024 + lane * 16;                \
      gload16(A + (size_t)(m0 + r) * K + (T)*64 + schunk * 8,             \
              (char*)&As[S][0] + ldso);                                   \
      gload16(BT + (size_t)(n0 + r) * K + (T)*64 + schunk * 8,            \
              (char*)&Bs[S][0] + ldso);                                   \
    }                                                                     \
  } while (0)

  f32x4 acc[4][4] = {};
  const int nt = K >> 6;  // K-tiles of 64
  STAGE4(0, 0);
  asm volatile("s_waitcnt vmcnt(0)" ::: "memory");
  __builtin_amdgcn_sched_barrier(0);
  __builtin_amdgcn_s_barrier();
  __builtin_amdgcn_sched_barrier(0);

#pragma unroll 1
  for (int t = 0; t < nt; ++t) {
    const int s = t & 1;
    if (t + 1 < nt) STAGE4(t + 1, s ^ 1);
    bf16x8 af[4][2], bfr[4][2];
#pragma unroll
    for (int m = 0; m < 4; ++m) {
      const int row = wr * 64 + m * 16 + c;
#pragma unroll
      for (int kk = 0; kk < 2; ++kk)
        af[m][kk] = *(const bf16x8*)((const char*)&As[s][0] + row * 128 +
                                     (((kk * 4 + g) ^ (row & 7)) << 4));
    }
#pragma unroll
    for (int n = 0; n < 4; ++n) {
      const int row = wc * 64 + n * 16 + c;
#pragma unroll
      for (int kk = 0; kk < 2; ++kk)
        bfr[n][kk] = *(const bf16x8*)((const char*)&Bs[s][0] + row * 128 +
                                      (((kk * 4 + g) ^ (row & 7)) << 4));
    }
    // no lgkm drain: compiler interleaves reads/MFMAs with counted lgkmcnt
    __builtin_amdgcn_s_setprio(1);
#pragma unroll
    for (int kk = 0; kk < 2; ++kk)
#pragma unroll
      for (int m = 0; m < 4; ++m)
#pragma unroll
        for (int n = 0; n < 4; ++n)
          acc[m][n] = mfma16(af[m][kk], bfr[n][kk], acc[m][n]);
    __builtin_amdgcn_s_setprio(0);
    if (t + 1 < nt) {
      asm volatile("s_waitcnt vmcnt(0)" ::: "memory");  // next slot landed
      __builtin_amdgcn_sched_barrier(0);
      __builtin_amdgcn_s_barrier();
      __builtin_amdgcn_sched_barrier(0);
    }
  }
#undef STAGE4
  // epilogue (r7-verified mapping)
#pragma unroll
  for (int m = 0; m < 4; ++m)
#pragma unroll
    for (int n = 0; n < 4; ++n)
#pragma unroll
      for (int i = 0; i < 4; ++i) {
        int row = m0 + wr * 64 + m * 16 + g * 4 + i;
        int col = n0 + wc * 64 + n * 16 + c;
        if (F32OUT)
          Cf[(size_t)row * N + col] = acc[m][n][i] + bias[col];
        else
          Cb[(size_t)row * N + col] = (bf16)acc[m][n][i];
      }
}

// ---------------- V transpose: VT[bh][d][pos] with kappa-ordered keys ------
__global__ __launch_bounds__(256) void transpose_v_kernel(const bf16* __restrict__ qkv,
                                                          bf16* __restrict__ vt) {
  __shared__ bf16 tl[64][72];  // stride 144B keeps 16B alignment for b128 stores
  const int tid = threadIdx.x;
  const int st = blockIdx.x, bh = blockIdx.y;
  const int b = bh >> 4, h = bh & 15;
#pragma unroll
  for (int it = 0; it < 2; ++it) {
    int idx = it * 256 + tid;          // 0..511
    int sl = idx >> 3, ch = idx & 7;   // sl 0..63 (s row), ch 0..7 (d chunk)
    bf16x8 v = *(const bf16x8*)(qkv + (size_t)(b * 2048 + st * 64 + sl) * 3072 + 2048 + h * 64 + ch * 8);
    *(bf16x8*)&tl[sl][ch * 8] = v;
  }
  __syncthreads();
#pragma unroll
  for (int it = 0; it < 2; ++it) {
    int idx = it * 256 + tid;
    int d = idx >> 3, ch = idx & 7;    // d 0..63, output chunk 0..7 (8 keys)
    const int blk = ch >> 2, g = ch & 3;  // 32-key block, frag group
    bf16x8 o;
#pragma unroll
    for (int j = 0; j < 8; ++j) {
      int loc = (j < 4) ? (4 * g + j) : (16 + 4 * g + (j - 4));  // kappa
      o[j] = tl[blk * 32 + loc][d];
    }
    *(bf16x8*)(vt + ((size_t)bh * 64 + d) * 2048 + st * 64 + ch * 8) = o;
  }
}

// ---------------- causal flash attention (r15 best version) ----------------
// Grid = 512 blocks x 512 threads (8 waves, 16 q-rows/wave), KVBLK=128.
// bh-major XCD mapping. Block does qt=x then 15-x. Single-barrier-per-tile
// skeleton; kappa-ordered VT; tree-max; defer-max (T13, THR=8).
__global__ __launch_bounds__(512, 4) void attn_kernel(const bf16* __restrict__ qkv,
                                                      const bf16* __restrict__ vt,
                                                      bf16* __restrict__ attn_out) {
  __shared__ bf16 Ks[2][128 * 64];   // [key][hd], chunk-swizzled, 16KB each
  __shared__ bf16 Vs[2][64 * 128];   // [d][kpos], chunk-swizzled, 16KB each
  const int tid = threadIdx.x, lane = tid & 63, wave = tid >> 6;
  const int g = lane >> 4, c = lane & 15;
  const int bid = blockIdx.x;
  const int xcd = bid & 7;
  const int x = (bid >> 3) & 7;
  const int bh = (bid >> 6) * 8 + xcd;
  const int b = bh >> 4, h = bh & 15;
  const float SCL = 0.125f * 1.4426950408889634f;  // log2(e) * scale

  bf16x8 ones;
#pragma unroll
  for (int j = 0; j < 8; ++j) ones[j] = (bf16)1.0f;

#define STAGE(KT, BUF)                                                                    \
  do {                                                                                    \
    _Pragma("unroll") for (int t2 = 0; t2 < 2; ++t2) {                                    \
      int o = t2 * 8192 + wave * 1024 + lane * 16; /* 0..16383 */                         \
      int rK = o >> 7, chK = (((o & 127) >> 4) ^ (rK & 7));                               \
      gload16((const char*)qkv +                                                          \
                  ((size_t)(b * 2048 + (KT)*128 + rK) * 3072 + 1024 + h * 64) * 2 +       \
                  (chK << 4),                                                             \
              (char*)Ks[BUF] + o);                                                        \
      int rV = o >> 8, chV = (((o & 255) >> 4) ^ (rV & 7));                               \
      gload16((const char*)vt + (((size_t)bh * 64 + rV) * 2048 + (KT)*128) * 2 +          \
                  (chV << 4),                                                             \
              (char*)Vs[BUF] + o);                                                        \
    }                                                                                     \
  } while (0)

#pragma unroll 1
  for (int ph = 0; ph < 2; ++ph) {
    const int qt = ph ? (15 - x) : x;
    const int qlow = qt * 128 + wave * 16;  // lowest q row of this wave

    bf16x8 qf[2];
#pragma unroll
    for (int kk = 0; kk < 2; ++kk) {
      size_t row = (size_t)(b * 2048 + qlow + c);
      qf[kk] = *(const bf16x8*)(qkv + row * 3072 + h * 64 + kk * 32 + g * 8);
    }

    f32x4 oacc[4] = {};
    f32x4 lacc = {};        // row-sums, oacc layout (q = qlow + 4g+i)
    float mrun = -3.0e38f;  // per-lane: q = qlow + c

    const int nkt = qt + 1;
    if (ph) {  // protect buf0 from the previous phase's last-tile readers
      __builtin_amdgcn_s_barrier();
      __builtin_amdgcn_sched_barrier(0);
    }
    STAGE(0, 0);
    asm volatile("s_waitcnt vmcnt(0)" ::: "memory");
    __builtin_amdgcn_sched_barrier(0);
    __builtin_amdgcn_s_barrier();
    __builtin_amdgcn_sched_barrier(0);
    for (int kt = 0; kt < nkt; ++kt) {
      const int cur = kt & 1;
      if (kt + 1 < nkt) STAGE(kt + 1, cur ^ 1);
      // QK^T swapped: sc[n] holds S[key = kt*128+n*16+4g+i][q = qlow+c]
      f32x4 sc[8] = {};
      __builtin_amdgcn_s_setprio(1);
#pragma unroll
      for (int n = 0; n < 8; ++n) {
        int key = n * 16 + c;
#pragma unroll
        for (int kk = 0; kk < 2; ++kk) {
          bf16x8 kf = *(const bf16x8*)((const char*)Ks[cur] + key * 128 +
                                       (((kk * 4 + g) ^ (key & 7)) << 4));
          sc[n] = mfma16(kf, qf[kk], sc[n]);
        }
      }
      __builtin_amdgcn_s_setprio(0);
      const int q = qlow + c;
      if (kt == qt) {  // diagonal tile: causal mask
#pragma unroll
        for (int n = 0; n < 8; ++n)
#pragma unroll
          for (int i = 0; i < 4; ++i)
            sc[n][i] = ((kt * 128 + n * 16 + 4 * g + i) <= q) ? sc[n][i] : -3.0e38f;
      }
      // tree max (depth ~5)
      float vmax;
      {
        float a[8];
#pragma unroll
        for (int n = 0; n < 8; ++n)
          a[n] = fmaxf(fmaxf(sc[n][0], sc[n][1]), fmaxf(sc[n][2], sc[n][3]));
        float b0 = fmaxf(a[0], a[1]), b1 = fmaxf(a[2], a[3]);
        float b2 = fmaxf(a[4], a[5]), b3 = fmaxf(a[6], a[7]);
        vmax = fmaxf(fmaxf(b0, b1), fmaxf(b2, b3));
      }
      vmax = fmaxf(vmax, __shfl_xor(vmax, 16));
      vmax = fmaxf(vmax, __shfl_xor(vmax, 32));
      const float mx = vmax * SCL;
      // defer-max (T13): rescale only when running max grew by >8 (log2)
      if (!__all(mx <= mrun + 8.0f)) {
        const float mnew = fmaxf(mrun, mx);
        const float fs = __builtin_amdgcn_exp2f(mrun - mnew);
        mrun = mnew;
#pragma unroll
        for (int i = 0; i < 4; ++i) {
          float fsb = __shfl(fs, ((lane >> 4) << 2) + i);
          lacc[i] *= fsb;
#pragma unroll
          for (int dn = 0; dn < 4; ++dn) oacc[dn][i] *= fsb;
        }
      }
#pragma unroll
      for (int n = 0; n < 8; ++n)
#pragma unroll
        for (int i = 0; i < 4; ++i)
          sc[n][i] = __builtin_amdgcn_exp2f(fmaf(sc[n][i], SCL, -mrun));
      // pack PV A-frags: key = kss*32 + (j<4 ? 4g+j : 16+4g+(j-4))
      bf16x8 pa[4];
#pragma unroll
      for (int kss = 0; kss < 4; ++kss) {
        bf16x8 t;
#pragma unroll
        for (int j = 0; j < 4; ++j) t[j] = (bf16)sc[2 * kss][j];
#pragma unroll
        for (int j = 0; j < 4; ++j) t[4 + j] = (bf16)sc[2 * kss + 1][j];
        pa[kss] = t;
      }
      // PV + row-sum via ones-MFMA; kappa-ordered Vs -> one b128 per (kss,dn)
      __builtin_amdgcn_s_setprio(1);
#pragma unroll
      for (int kss = 0; kss < 4; ++kss) {
        lacc = mfma16(pa[kss], ones, lacc);
#pragma unroll
        for (int dn = 0; dn < 4; ++dn) {
          const int d = dn * 16 + c;
          bf16x8 vb = *(const bf16x8*)((const char*)Vs[cur] + d * 256 +
                                       (((kss * 4 + g) ^ (d & 7)) << 4));
          oacc[dn] = mfma16(pa[kss], vb, oacc[dn]);
        }
      }
      __builtin_amdgcn_s_setprio(0);
      if (kt + 1 < nkt) {
        asm volatile("s_waitcnt vmcnt(0)" ::: "memory");  // kt+1 landed (free)
        __builtin_amdgcn_sched_barrier(0);
        __builtin_amdgcn_s_barrier();  // publish kt+1; readers of cur done
        __builtin_amdgcn_sched_barrier(0);
      }
    }
    // epilogue: normalize, store bf16 [8192][1024]
#pragma unroll
    for (int i = 0; i < 4; ++i) {
      float inv = __builtin_amdgcn_rcpf(lacc[i]);
      size_t row = (size_t)(b * 2048 + qlow + 4 * g + i);
#pragma unroll
      for (int dn = 0; dn < 4; ++dn)
        attn_out[row * 1024 + h * 64 + dn * 16 + c] = (bf16)(oacc[dn][i] * inv);
    }
  }
#undef STAGE
}

// ---------------- launch ----------------
extern "C" void kernel_launch(void* const* d_in, const int* in_sizes, int n_in,
                              void* d_out, int out_size, void* d_ws, size_t ws_size,
                              hipStream_t stream) {
  const float* x  = (const float*)d_in[0];
  const float* Wq = (const float*)d_in[1];
  const float* Wk = (const float*)d_in[2];
  const float* Wv = (const float*)d_in[3];
  const float* Wo = (const float*)d_in[4];
  const float* bo = (const float*)d_in[5];
  float* out = (float*)d_out;
  char* ws = (char*)d_ws;

  bf16* Xb    = (bf16*)(ws);
  bf16* WqkvT = (bf16*)(ws + 16777216);
  bf16* WoT   = (bf16*)(ws + 23068672);
  bf16* QKV   = (bf16*)(ws + 25165824);
  bf16* VT    = (bf16*)(ws + 75497472);
  bf16* AttnO = (bf16*)(ws + 92274688);

  pack_all_kernel<<<2048, 256, 0, stream>>>(x, Wq, Wk, Wv, Wo, Xb, WqkvT, WoT);
  gemm4_kernel<false><<<1536, 256, 0, stream>>>(Xb, WqkvT, QKV, nullptr, nullptr,
                                                3072, 1024);
  transpose_v_kernel<<<dim3(32, 64), 256, 0, stream>>>(QKV, VT);
  attn_kernel<<<512, 512, 0, stream>>>(QKV, VT, AttnO);
  gemm4_kernel<true><<<512, 256, 0, stream>>>(AttnO, WoT, nullptr, out, bo,
                                              1024, 1024);
}

// Round 20
// 160.578 us; speedup vs baseline: 1.1047x; 1.0443x over previous
//
#include <hip/hip_runtime.h>

// B=4, S=2048, D=1024, H=16, HS=64. Full bf16-MFMA pipeline.
// Workspace layout (needs ~104 MiB):
//   Xb     @ 0         : x as bf16            [8192][1024]   16 MiB
//   WqkvT  @ 16777216  : qkv weights B^T bf16 [3072][1024]    6 MiB
//   WoT    @ 23068672  : Wo^T bf16            [1024][1024]    2 MiB
//   QKV    @ 25165824  : Q|K|V bf16           [8192][3072]   48 MiB (V cols unwritten)
//   VT     @ 75497472  : V^T bf16, kappa-ordered keys  [64bh][64][2048] 16 MiB
//   AttnO  @ 92274688  : attention out bf16   [8192][1024]   16 MiB

typedef __bf16 bf16;
typedef bf16 bf16x8 __attribute__((ext_vector_type(8)));
typedef bf16 bf16x4 __attribute__((ext_vector_type(4)));
typedef float f32x4 __attribute__((ext_vector_type(4)));

__device__ __forceinline__ void gload16(const void* gsrc, void* ldst) {
  __builtin_amdgcn_global_load_lds(
      (const __attribute__((address_space(1))) unsigned int*)gsrc,
      (__attribute__((address_space(3))) unsigned int*)ldst, 16, 0, 0);
}

__device__ __forceinline__ f32x4 mfma16(bf16x8 a, bf16x8 b, f32x4 c) {
  return __builtin_amdgcn_mfma_f32_16x16x32_bf16(a, b, c, 0, 0, 0);
}

// ---------------- fused pack kernel (one launch) ----------------
__global__ __launch_bounds__(256) void pack_all_kernel(const float* __restrict__ x,
                                                       const float* __restrict__ Wq,
                                                       const float* __restrict__ Wk,
                                                       const float* __restrict__ Wv,
                                                       const float* __restrict__ Wo,
                                                       bf16* __restrict__ xb,
                                                       bf16* __restrict__ WT,
                                                       bf16* __restrict__ WoT) {
  const int stride = gridDim.x * 256;
  const int t0 = blockIdx.x * 256 + threadIdx.x;
  for (int i = t0; i < 2097152; i += stride) {
    float4 v = *(const float4*)(x + (size_t)i * 4);
    bf16x4 o;
    o[0] = (bf16)v.x; o[1] = (bf16)v.y; o[2] = (bf16)v.z; o[3] = (bf16)v.w;
    *(bf16x4*)(xb + (size_t)i * 4) = o;
  }
  for (int idx = t0; idx < 3145728; idx += stride) {
    int n = idx >> 10, k = idx & 1023;
    int sel = n >> 10, nn = n & 1023;
    const float* W = (sel == 0) ? Wq : (sel == 1 ? Wk : Wv);
    int h = nn >> 6, e = nn & 63;
    WT[(size_t)n * 1024 + k] = (bf16)W[h * 65536 + k * 64 + e];
  }
  for (int idx = t0; idx < 1048576; idx += stride) {
    int n = idx >> 10, k = idx & 1023;
    WoT[idx] = (bf16)Wo[k * 1024 + n];
  }
}

// ---------------- GEMM v4 (session best) + fused VT epilogue ----------------
// Per-wave 64x64 (32 FLOP per LDS byte), BM=BN=128, BK=64, 256 threads
// (4 waves 2x2), 2 LDS slots (64KB) -> 2 blocks/CU. One barrier + one
// vmcnt(0) per K-tile; no lgkm fence. 3-bit XOR chunk swizzle;
// n-major-per-XCD mapping.
// r20 fusion: V-columns of QKV (n0 >= 2048) are consumed ONLY via VT, so
// V-blocks skip the C-write and instead produce kappa-ordered VT directly:
// barrier -> acc into padded 128x130 LDS tile transposed (tl2[hd][s]) ->
// barrier -> bf16x8 writes with transpose_v's verified kappa write logic.
// Eliminates the standalone transpose kernel + one launch gap.
template <bool F32OUT>
__global__ __launch_bounds__(256, 2) void gemm4_kernel(const bf16* __restrict__ A,
                                                       const bf16* __restrict__ BT,
                                                       bf16* __restrict__ Cb,
                                                       float* __restrict__ Cf,
                                                       const float* __restrict__ bias,
                                                       bf16* __restrict__ VT,
                                                       int N, int K) {
  __shared__ bf16 As[2][128 * 64];  // [slot][row][k], chunk-swizzled
  __shared__ bf16 Bs[2][128 * 64];
  const int tid = threadIdx.x, lane = tid & 63, wave = tid >> 6;
  const int g = lane >> 4, c = lane & 15;
  const int wr = wave >> 1, wc = wave & 1;
  const int bid = blockIdx.x;
  const int xcd = bid & 7, local = bid >> 3;
  const int m0 = (xcd * 8 + (local & 7)) * 128;
  const int n0 = (local >> 3) * 128;

  const int schunk = (lane & 7) ^ (lane >> 3);  // source k-chunk for staging

#define STAGE4(T, S)                                                      \
  do {                                                                    \
    _Pragma("unroll") for (int j = 0; j < 4; ++j) {                       \
      const int r = wave * 32 + j * 8 + (lane >> 3);                      \
      const int ldso = wave * 4096 + j * 1024 + lane * 16;                \
      gload16(A + (size_t)(m0 + r) * K + (T)*64 + schunk * 8,             \
              (char*)&As[S][0] + ldso);                                   \
      gload16(BT + (size_t)(n0 + r) * K + (T)*64 + schunk * 8,            \
              (char*)&Bs[S][0] + ldso);                                   \
    }                                                                     \
  } while (0)

  f32x4 acc[4][4] = {};
  const int nt = K >> 6;  // K-tiles of 64
  STAGE4(0, 0);
  asm volatile("s_waitcnt vmcnt(0)" ::: "memory");
  __builtin_amdgcn_sched_barrier(0);
  __builtin_amdgcn_s_barrier();
  __builtin_amdgcn_sched_barrier(0);

#pragma unroll 1
  for (int t = 0; t < nt; ++t) {
    const int s = t & 1;
    if (t + 1 < nt) STAGE4(t + 1, s ^ 1);
    bf16x8 af[4][2], bfr[4][2];
#pragma unroll
    for (int m = 0; m < 4; ++m) {
      const int row = wr * 64 + m * 16 + c;
#pragma unroll
      for (int kk = 0; kk < 2; ++kk)
        af[m][kk] = *(const bf16x8*)((const char*)&As[s][0] + row * 128 +
                                     (((kk * 4 + g) ^ (row & 7)) << 4));
    }
#pragma unroll
    for (int n = 0; n < 4; ++n) {
      const int row = wc * 64 + n * 16 + c;
#pragma unroll
      for (int kk = 0; kk < 2; ++kk)
        bfr[n][kk] = *(const bf16x8*)((const char*)&Bs[s][0] + row * 128 +
                                      (((kk * 4 + g) ^ (row & 7)) << 4));
    }
    // no lgkm drain: compiler interleaves reads/MFMAs with counted lgkmcnt
    __builtin_amdgcn_s_setprio(1);
#pragma unroll
    for (int kk = 0; kk < 2; ++kk)
#pragma unroll
      for (int m = 0; m < 4; ++m)
#pragma unroll
        for (int n = 0; n < 4; ++n)
          acc[m][n] = mfma16(af[m][kk], bfr[n][kk], acc[m][n]);
    __builtin_amdgcn_s_setprio(0);
    if (t + 1 < nt) {
      asm volatile("s_waitcnt vmcnt(0)" ::: "memory");  // next slot landed
      __builtin_amdgcn_sched_barrier(0);
      __builtin_amdgcn_s_barrier();
      __builtin_amdgcn_sched_barrier(0);
    }
  }
#undef STAGE4
  if (!F32OUT && VT != nullptr && n0 >= 2048) {
    // V-block: emit kappa-ordered transposed VT instead of Cb.
    __builtin_amdgcn_s_barrier();  // all waves' main-loop LDS reads done
    __builtin_amdgcn_sched_barrier(0);
    bf16* tl2 = (bf16*)&As[0][0];  // 128 x 130 tile (33.3KB <= 64KB)
#pragma unroll
    for (int m = 0; m < 4; ++m)
#pragma unroll
      for (int n = 0; n < 4; ++n)
#pragma unroll
        for (int i = 0; i < 4; ++i) {
          int r_loc = wr * 64 + m * 16 + g * 4 + i;  // s offset 0..127
          int c_loc = wc * 64 + n * 16 + c;          // hd offset 0..127
          tl2[c_loc * 130 + r_loc] = (bf16)acc[m][n][i];
        }
    __builtin_amdgcn_s_barrier();
    __builtin_amdgcn_sched_barrier(0);
    const int bh0 = ((m0 >> 11) << 4) + ((n0 - 2048) >> 6);  // b*16 + h0
    const int s0 = m0 & 2047;
#pragma unroll
    for (int it = 0; it < 8; ++it) {
      int idx = it * 256 + tid;        // 0..2047
      int hd = idx >> 4, ch = idx & 15;  // hd row, s-chunk of 8
      int blk = ch >> 2, gg = ch & 3;    // 32-key block, frag group (kappa)
      bf16x8 o;
#pragma unroll
      for (int j = 0; j < 8; ++j) {
        int loc = (j < 4) ? (4 * gg + j) : (16 + 4 * gg + (j - 4));  // kappa
        o[j] = tl2[hd * 130 + blk * 32 + loc];
      }
      *(bf16x8*)(VT + ((size_t)(bh0 + (hd >> 6)) * 64 + (hd & 63)) * 2048 +
                 s0 + ch * 8) = o;
    }
  } else {
    // Q/K blocks and out-projection: normal C-write (r7-verified mapping)
#pragma unroll
    for (int m = 0; m < 4; ++m)
#pragma unroll
      for (int n = 0; n < 4; ++n)
#pragma unroll
        for (int i = 0; i < 4; ++i) {
          int row = m0 + wr * 64 + m * 16 + g * 4 + i;
          int col = n0 + wc * 64 + n * 16 + c;
          if (F32OUT)
            Cf[(size_t)row * N + col] = acc[m][n][i] + bias[col];
          else
            Cb[(size_t)row * N + col] = (bf16)acc[m][n][i];
        }
  }
}

// ---------------- causal flash attention (r15 best version) ----------------
// Grid = 512 blocks x 512 threads (8 waves, 16 q-rows/wave), KVBLK=128.
// bh-major XCD mapping. Block does qt=x then 15-x. Single-barrier-per-tile
// skeleton; kappa-ordered VT; tree-max; defer-max (T13, THR=8).
__global__ __launch_bounds__(512, 4) void attn_kernel(const bf16* __restrict__ qkv,
                                                      const bf16* __restrict__ vt,
                                                      bf16* __restrict__ attn_out) {
  __shared__ bf16 Ks[2][128 * 64];   // [key][hd], chunk-swizzled, 16KB each
  __shared__ bf16 Vs[2][64 * 128];   // [d][kpos], chunk-swizzled, 16KB each
  const int tid = threadIdx.x, lane = tid & 63, wave = tid >> 6;
  const int g = lane >> 4, c = lane & 15;
  const int bid = blockIdx.x;
  const int xcd = bid & 7;
  const int x = (bid >> 3) & 7;
  const int bh = (bid >> 6) * 8 + xcd;
  const int b = bh >> 4, h = bh & 15;
  const float SCL = 0.125f * 1.4426950408889634f;  // log2(e) * scale

  bf16x8 ones;
#pragma unroll
  for (int j = 0; j < 8; ++j) ones[j] = (bf16)1.0f;

#define STAGE(KT, BUF)                                                                    \
  do {                                                                                    \
    _Pragma("unroll") for (int t2 = 0; t2 < 2; ++t2) {                                    \
      int o = t2 * 8192 + wave * 1024 + lane * 16; /* 0..16383 */                         \
      int rK = o >> 7, chK = (((o & 127) >> 4) ^ (rK & 7));                               \
      gload16((const char*)qkv +                                                          \
                  ((size_t)(b * 2048 + (KT)*128 + rK) * 3072 + 1024 + h * 64) * 2 +       \
                  (chK << 4),                                                             \
              (char*)Ks[BUF] + o);                                                        \
      int rV = o >> 8, chV = (((o & 255) >> 4) ^ (rV & 7));                               \
      gload16((const char*)vt + (((size_t)bh * 64 + rV) * 2048 + (KT)*128) * 2 +          \
                  (chV << 4),                                                             \
              (char*)Vs[BUF] + o);                                                        \
    }                                                                                     \
  } while (0)

#pragma unroll 1
  for (int ph = 0; ph < 2; ++ph) {
    const int qt = ph ? (15 - x) : x;
    const int qlow = qt * 128 + wave * 16;  // lowest q row of this wave

    bf16x8 qf[2];
#pragma unroll
    for (int kk = 0; kk < 2; ++kk) {
      size_t row = (size_t)(b * 2048 + qlow + c);
      qf[kk] = *(const bf16x8*)(qkv + row * 3072 + h * 64 + kk * 32 + g * 8);
    }

    f32x4 oacc[4] = {};
    f32x4 lacc = {};        // row-sums, oacc layout (q = qlow + 4g+i)
    float mrun = -3.0e38f;  // per-lane: q = qlow + c

    const int nkt = qt + 1;
    if (ph) {  // protect buf0 from the previous phase's last-tile readers
      __builtin_amdgcn_s_barrier();
      __builtin_amdgcn_sched_barrier(0);
    }
    STAGE(0, 0);
    asm volatile("s_waitcnt vmcnt(0)" ::: "memory");
    __builtin_amdgcn_sched_barrier(0);
    __builtin_amdgcn_s_barrier();
    __builtin_amdgcn_sched_barrier(0);
    for (int kt = 0; kt < nkt; ++kt) {
      const int cur = kt & 1;
      if (kt + 1 < nkt) STAGE(kt + 1, cur ^ 1);
      // QK^T swapped: sc[n] holds S[key = kt*128+n*16+4g+i][q = qlow+c]
      f32x4 sc[8] = {};
      __builtin_amdgcn_s_setprio(1);
#pragma unroll
      for (int n = 0; n < 8; ++n) {
        int key = n * 16 + c;
#pragma unroll
        for (int kk = 0; kk < 2; ++kk) {
          bf16x8 kf = *(const bf16x8*)((const char*)Ks[cur] + key * 128 +
                                       (((kk * 4 + g) ^ (key & 7)) << 4));
          sc[n] = mfma16(kf, qf[kk], sc[n]);
        }
      }
      __builtin_amdgcn_s_setprio(0);
      const int q = qlow + c;
      if (kt == qt) {  // diagonal tile: causal mask
#pragma unroll
        for (int n = 0; n < 8; ++n)
#pragma unroll
          for (int i = 0; i < 4; ++i)
            sc[n][i] = ((kt * 128 + n * 16 + 4 * g + i) <= q) ? sc[n][i] : -3.0e38f;
      }
      // tree max (depth ~5)
      float vmax;
      {
        float a[8];
#pragma unroll
        for (int n = 0; n < 8; ++n)
          a[n] = fmaxf(fmaxf(sc[n][0], sc[n][1]), fmaxf(sc[n][2], sc[n][3]));
        float b0 = fmaxf(a[0], a[1]), b1 = fmaxf(a[2], a[3]);
        float b2 = fmaxf(a[4], a[5]), b3 = fmaxf(a[6], a[7]);
        vmax = fmaxf(fmaxf(b0, b1), fmaxf(b2, b3));
      }
      vmax = fmaxf(vmax, __shfl_xor(vmax, 16));
      vmax = fmaxf(vmax, __shfl_xor(vmax, 32));
      const float mx = vmax * SCL;
      // defer-max (T13): rescale only when running max grew by >8 (log2)
      if (!__all(mx <= mrun + 8.0f)) {
        const float mnew = fmaxf(mrun, mx);
        const float fs = __builtin_amdgcn_exp2f(mrun - mnew);
        mrun = mnew;
#pragma unroll
        for (int i = 0; i < 4; ++i) {
          float fsb = __shfl(fs, ((lane >> 4) << 2) + i);
          lacc[i] *= fsb;
#pragma unroll
          for (int dn = 0; dn < 4; ++dn) oacc[dn][i] *= fsb;
        }
      }
#pragma unroll
      for (int n = 0; n < 8; ++n)
#pragma unroll
        for (int i = 0; i < 4; ++i)
          sc[n][i] = __builtin_amdgcn_exp2f(fmaf(sc[n][i], SCL, -mrun));
      // pack PV A-frags: key = kss*32 + (j<4 ? 4g+j : 16+4g+(j-4))
      bf16x8 pa[4];
#pragma unroll
      for (int kss = 0; kss < 4; ++kss) {
        bf16x8 t;
#pragma unroll
        for (int j = 0; j < 4; ++j) t[j] = (bf16)sc[2 * kss][j];
#pragma unroll
        for (int j = 0; j < 4; ++j) t[4 + j] = (bf16)sc[2 * kss + 1][j];
        pa[kss] = t;
      }
      // PV + row-sum via ones-MFMA; kappa-ordered Vs -> one b128 per (kss,dn)
      __builtin_amdgcn_s_setprio(1);
#pragma unroll
      for (int kss = 0; kss < 4; ++kss) {
        lacc = mfma16(pa[kss], ones, lacc);
#pragma unroll
        for (int dn = 0; dn < 4; ++dn) {
          const int d = dn * 16 + c;
          bf16x8 vb = *(const bf16x8*)((const char*)Vs[cur] + d * 256 +
                                       (((kss * 4 + g) ^ (d & 7)) << 4));
          oacc[dn] = mfma16(pa[kss], vb, oacc[dn]);
        }
      }
      __builtin_amdgcn_s_setprio(0);
      if (kt + 1 < nkt) {
        asm volatile("s_waitcnt vmcnt(0)" ::: "memory");  // kt+1 landed (free)
        __builtin_amdgcn_sched_barrier(0);
        __builtin_amdgcn_s_barrier();  // publish kt+1; readers of cur done
        __builtin_amdgcn_sched_barrier(0);
      }
    }
    // epilogue: normalize, store bf16 [8192][1024]
#pragma unroll
    for (int i = 0; i < 4; ++i) {
      float inv = __builtin_amdgcn_rcpf(lacc[i]);
      size_t row = (size_t)(b * 2048 + qlow + 4 * g + i);
#pragma unroll
      for (int dn = 0; dn < 4; ++dn)
        attn_out[row * 1024 + h * 64 + dn * 16 + c] = (bf16)(oacc[dn][i] * inv);
    }
  }
#undef STAGE
}

// ---------------- launch ----------------
extern "C" void kernel_launch(void* const* d_in, const int* in_sizes, int n_in,
                              void* d_out, int out_size, void* d_ws, size_t ws_size,
                              hipStream_t stream) {
  const float* x  = (const float*)d_in[0];
  const float* Wq = (const float*)d_in[1];
  const float* Wk = (const float*)d_in[2];
  const float* Wv = (const float*)d_in[3];
  const float* Wo = (const float*)d_in[4];
  const float* bo = (const float*)d_in[5];
  float* out = (float*)d_out;
  char* ws = (char*)d_ws;

  bf16* Xb    = (bf16*)(ws);
  bf16* WqkvT = (bf16*)(ws + 16777216);
  bf16* WoT   = (bf16*)(ws + 23068672);
  bf16* QKV   = (bf16*)(ws + 25165824);
  bf16* VT    = (bf16*)(ws + 75497472);
  bf16* AttnO = (bf16*)(ws + 92274688);

  pack_all_kernel<<<2048, 256, 0, stream>>>(x, Wq, Wk, Wv, Wo, Xb, WqkvT, WoT);
  gemm4_kernel<false><<<1536, 256, 0, stream>>>(Xb, WqkvT, QKV, nullptr, nullptr,
                                                VT, 3072, 1024);
  attn_kernel<<<512, 512, 0, stream>>>(QKV, VT, AttnO);
  gemm4_kernel<true><<<512, 256, 0, stream>>>(AttnO, WoT, nullptr, out, bo,
                                              nullptr, 1024, 1024);
}